// Round 1
// 62.733 us; speedup vs baseline: 1.0715x; 1.0715x over previous
//
#include <hip/hip_runtime.h>

// One thread per sample. Heisenberg-picture formulation: the pre-CNOT state
// is a full tensor product v0 x v1 x v2 x v3 (encoder rotation + per-wire
// trainable Rz*Ry*Rx collapsed into T_q). Instead of materializing the
// 16-amplitude state and applying CNOT index swaps, the measured observables
// O_w = cos(t_w) Z_w + sin(t_w) Y_w (final Rx layer folded into measurement)
// are conjugated backwards through CNOT(0,1),CNOT(1,2),CNOT(2,3),CNOT(3,0):
//   Z'_0 = Z1 Z2 Z3             Y'_0 =  X0 Y1 Z2 Z3
//   Z'_1 = Z0 Z1                Y'_1 =  Z0 Y1 X2
//   Z'_2 = Z0 Z1 Z2             Y'_2 =  Z0 Z1 Y2 X3
//   Z'_3 = Z0 Z1 Z2 Z3          Y'_3 = -Y0 Y1 Z2 Y3   (ZX=iY twice -> -1)
// Expectations of Pauli strings on a product state factorize into per-wire
// scalars: z=|a|^2-|b|^2, X=Re(conj(a)b), Y=Im(conj(a)b) (true <X>,<Y> carry
// a factor 2 each, folded into the stored sin constants: 4*sin for wires
// 0..2, -8*sin for wire 3). ~90 VALU ops/thread vs ~400 for the explicit
// 16-amplitude version.
// Dtypes: inputs fp32 [n,4], theta fp32 [16], out fp32 [n,4,1].
// Encoder trig uses native v_sin_f32/v_cos_f32 (__sinf/__cosf): HW abs err
// ~1e-5 << 8.28e-3 threshold; precise __sincosf kept for shared theta consts.

__global__ __launch_bounds__(256) void qsim_kernel(
        const float* __restrict__ x,      // [n,4] float32
        const float* __restrict__ theta,  // [16]  float32
        float* __restrict__ out,          // [n,4] float32
        int n) {
    // ---- per-block: compose trainable constants into LDS (lanes 0..3) ----
    __shared__ __align__(16) float cst[40];
    int tid = threadIdx.x;
    if (tid < 4) {
        int q = tid;
        float a = theta[3*q], bb = theta[3*q+1], c = theta[3*q+2];
        float sa, ca, sb, cb, sc, cc;
        __sincosf(0.5f*a,  &sa, &ca);
        __sincosf(0.5f*bb, &sb, &cb);
        __sincosf(0.5f*c,  &sc, &cc);
        // M = Ry(bb) * Rx(a)
        float m00r =  cb*ca, m00i =  sb*sa;
        float m01r = -sb*ca, m01i = -cb*sa;
        float m10r =  sb*ca, m10i = -cb*sa;
        float m11r =  cb*ca, m11i = -sb*sa;
        // T = Rz(c) * M : row0 *= (cc - i sc), row1 *= (cc + i sc)
        float* Tq = cst + 8*q;
        Tq[0] = cc*m00r + sc*m00i;  Tq[1] = cc*m00i - sc*m00r;
        Tq[2] = cc*m01r + sc*m01i;  Tq[3] = cc*m01i - sc*m01r;
        Tq[4] = cc*m10r - sc*m10i;  Tq[5] = cc*m10i + sc*m10r;
        Tq[6] = cc*m11r - sc*m11i;  Tq[7] = cc*m11i + sc*m11r;
        // final rx(theta[12+q]) folded into measurement:
        //   out_w = cos * <Z'_w> + sin * <Y'_w>;  <X>,<Y> factors of 2 and
        //   the Y'_3 string sign folded here.
        float sfq, cfq;
        __sincosf(theta[12+q], &sfq, &cfq);
        cst[32+q] = cfq;
        cst[36+q] = (q == 3 ? -8.0f : 4.0f) * sfq;
    }
    __syncthreads();

    int b = blockIdx.x * 256 + tid;
    if (b >= n) return;

    float4 xv = ((const float4*)x)[b];

    // broadcast constants from LDS
    float T[32];
    #pragma unroll
    for (int i = 0; i < 8; ++i) ((float4*)T)[i] = ((const float4*)cst)[i];
    float4 cf = ((const float4*)cst)[8];
    float4 sf = ((const float4*)cst)[9];

    // native HW trig: v_sin_f32 / v_cos_f32
    float s0 = __sinf(0.5f*xv.x), c0 = __cosf(0.5f*xv.x);
    float s1 = __sinf(0.5f*xv.y), c1 = __cosf(0.5f*xv.y);
    float s2 = __sinf(0.5f*xv.z), c2 = __cosf(0.5f*xv.z);
    float s3 = __sinf(0.5f*xv.w), c3 = __cosf(0.5f*xv.w);

    // v_q = T_q * (Enc_q |0>), a = component |0>, b = component |1>
    float var[4], vai[4], vbr[4], vbi[4];
    {   // wire0: rx(x0): e = (c0, -i s0)
        const float* t = T + 0;
        var[0] = t[0]*c0 + t[3]*s0;  vai[0] = t[1]*c0 - t[2]*s0;
        vbr[0] = t[4]*c0 + t[7]*s0;  vbi[0] = t[5]*c0 - t[6]*s0;
    }
    {   // wire1: ry(x1): e = (c1, s1)
        const float* t = T + 8;
        var[1] = t[0]*c1 + t[2]*s1;  vai[1] = t[1]*c1 + t[3]*s1;
        vbr[1] = t[4]*c1 + t[6]*s1;  vbi[1] = t[5]*c1 + t[7]*s1;
    }
    {   // wire2: rz(x2): e = (c2 - i s2, 0) -> v = (c2 - i s2) * T[:,0]
        const float* t = T + 16;
        var[2] = t[0]*c2 + t[1]*s2;  vai[2] = t[1]*c2 - t[0]*s2;
        vbr[2] = t[4]*c2 + t[5]*s2;  vbi[2] = t[5]*c2 - t[4]*s2;
    }
    {   // wire3: rx(x3)
        const float* t = T + 24;
        var[3] = t[0]*c3 + t[3]*s3;  vai[3] = t[1]*c3 - t[2]*s3;
        vbr[3] = t[4]*c3 + t[7]*s3;  vbi[3] = t[5]*c3 - t[6]*s3;
    }

    // per-wire single-qubit expectations on the product state
    // z = |a|^2 - |b|^2, X = Re(conj(a) b), Y = Im(conj(a) b)
    float zq[4], Xq[4], Yq[4];
    #pragma unroll
    for (int w = 0; w < 4; ++w) {
        float p0 = var[w]*var[w] + vai[w]*vai[w];
        float p1 = vbr[w]*vbr[w] + vbi[w]*vbi[w];
        zq[w] = p0 - p1;
        Xq[w] = var[w]*vbr[w] + vai[w]*vbi[w];   // X1 unused -> DCE'd
        Yq[w] = var[w]*vbi[w] - vai[w]*vbr[w];
    }

    // pulled-back observables (factors 2/sign folded into sf)
    float z01 = zq[0]*zq[1];
    float z23 = zq[2]*zq[3];
    float4 o;
    o.x = (cf.x*zq[1] + sf.x*(Xq[0]*Yq[1])) * z23;
    o.y = (cf.y*zq[1] + sf.y*(Yq[1]*Xq[2])) * zq[0];
    o.z = (cf.z*zq[2] + sf.z*(Yq[2]*Xq[3])) * z01;
    o.w = cf.w*(z01*z23) + sf.w*((Yq[0]*Yq[1])*(zq[2]*Yq[3]));
    ((float4*)out)[b] = o;
}

extern "C" void kernel_launch(void* const* d_in, const int* in_sizes, int n_in,
                              void* d_out, int out_size, void* d_ws, size_t ws_size,
                              hipStream_t stream) {
    const float* inputs = (const float*)d_in[0];
    const float* theta  = (const float*)d_in[1];
    float* out = (float*)d_out;
    int n = in_sizes[0] / 4;
    int blocks = (n + 255) / 256;
    qsim_kernel<<<blocks, 256, 0, stream>>>(inputs, theta, out, n);
}

// Round 2
// 62.047 us; speedup vs baseline: 1.0833x; 1.0111x over previous
//
#include <hip/hip_runtime.h>

// One thread per sample, fully Bloch-space formulation.
// The pre-CNOT state is a tensor product; every measured observable is a
// pulled-back Pauli string (Heisenberg through the 4 CNOTs):
//   Z'_0 = Z1 Z2 Z3             Y'_0 =  X0 Y1 Z2 Z3
//   Z'_1 = Z0 Z1                Y'_1 =  Z0 Y1 X2
//   Z'_2 = Z0 Z1 Z2             Y'_2 =  Z0 Z1 Y2 X3
//   Z'_3 = Z0 Z1 Z2 Z3          Y'_3 = -Y0 Y1 Z2 Y3
// Product-state expectations factorize into per-wire Bloch components
// (<X>,<Y>,<Z>). Per wire: trainable Rz(c)Ry(b)Rx(a) is a 3x3 real rotation
// R_q (block constant); encoder Bloch vectors are trivial:
//   rx(x0)|0> -> (0,-sin x0,cos x0); ry(x1)|0> -> (sin x1,0,cos x1);
//   rz(x2)|0> -> (0,0,1)  [x2 is INERT: rz on |0> is a global phase];
//   rx(x3)|0> -> (0,-sin x3,cos x3).
// So wire-q Bloch = sin*col_i(R_q) + cos*col2(R_q); wire 2's Bloch is the
// constant col2(R_2), folded into the output coefficients A_w,B_w.
// Final Rx layer folded into measurement: out_w = cos(t_w)<Z'_w> + sin(t_w)<Y'_w>.
// ~45 VALU ops/thread (was ~100), 6 transcendentals (was 8).
// Dtypes: inputs fp32 [n,4], theta fp32 [16], out fp32 [n,4,1].
// Encoder trig uses native v_sin_f32/v_cos_f32 (abs err ~1e-5 << 8.28e-3
// threshold); precise __sincosf for the shared theta constants.

__global__ __launch_bounds__(256) void qsim_kernel(
        const float* __restrict__ x,      // [n,4] float32
        const float* __restrict__ theta,  // [16]  float32
        float* __restrict__ out,          // [n,4] float32
        int n) {
    __shared__ __align__(16) float cst[32];
    int tid = threadIdx.x;
    int b = blockIdx.x * 256 + tid;

    // issue the sample load early so its latency overlaps the constant setup
    float4 xv = ((const float4*)x)[min(b, n - 1)];

    // ---- per-block: Bloch-rotation constants into LDS (lanes 0..3) ----
    if (tid < 4) {
        int q = tid;
        float sa, ca, sb, cb, sc, cc;
        __sincosf(theta[3*q],   &sa, &ca);   // full angles: Bloch rotations
        __sincosf(theta[3*q+1], &sb, &cb);
        __sincosf(theta[3*q+2], &sc, &cc);
        // R_q = Rz(c)*Ry(b)*Rx(a) columns:
        //   col0 = (cc*cb,            sc*cb,            -sb   )
        //   col1 = (cc*sb*sa - sc*ca, sc*sb*sa + cc*ca, cb*sa )
        //   col2 = (cc*sb*ca + sc*sa, sc*sb*ca - cc*sa, cb*ca )
        // wire-2 Bloch constants (redundant per lane, needed for A/B):
        float sa2, ca2, sb2, cb2, sc2, cc2;
        __sincosf(theta[6], &sa2, &ca2);
        __sincosf(theta[7], &sb2, &cb2);
        __sincosf(theta[8], &sc2, &cc2);
        float X2c = cc2*sb2*ca2 + sc2*sa2;
        float Y2c = sc2*sb2*ca2 - cc2*sa2;
        float Z2c = cb2*ca2;
        float sf, cf;
        __sincosf(theta[12+q], &sf, &cf);
        float A, Bc;
        if (q == 0)      { A = cf*Z2c; Bc =  sf*Z2c; }
        else if (q == 1) { A = cf;     Bc =  sf*X2c; }
        else if (q == 2) { A = cf*Z2c; Bc =  sf*Y2c; }
        else             { A = cf*Z2c; Bc = -sf*Z2c; }
        cst[24+q] = A; cst[28+q] = Bc;
        if (q == 0) {        // wire0 uses col1, col2
            cst[0]=cc*sb*sa - sc*ca; cst[1]=sc*sb*sa + cc*ca; cst[2]=cb*sa; cst[3]=0.f;
            cst[4]=cc*sb*ca + sc*sa; cst[5]=sc*sb*ca - cc*sa; cst[6]=cb*ca; cst[7]=0.f;
        } else if (q == 1) { // wire1 uses col0, col2
            cst[8]=cc*cb;  cst[9]=sc*cb; cst[10]=-sb; cst[11]=0.f;
            cst[12]=cc*sb*ca + sc*sa; cst[13]=sc*sb*ca - cc*sa; cst[14]=cb*ca; cst[15]=0.f;
        } else if (q == 3) { // wire3 uses col1, col2
            cst[16]=cc*sb*sa - sc*ca; cst[17]=sc*sb*sa + cc*ca; cst[18]=cb*sa; cst[19]=0.f;
            cst[20]=cc*sb*ca + sc*sa; cst[21]=sc*sb*ca - cc*sa; cst[22]=cb*ca; cst[23]=0.f;
        }
    }
    __syncthreads();

    if (b >= n) return;

    // broadcast constants from LDS (8x ds_read_b128)
    float C[32];
    #pragma unroll
    for (int i = 0; i < 8; ++i) ((float4*)C)[i] = ((const float4*)cst)[i];

    // native HW trig, full angles; xv.z (x2) provably unused
    float s0 = __sinf(xv.x), c0 = __cosf(xv.x);
    float s1 = __sinf(xv.y), c1 = __cosf(xv.y);
    float s3 = __sinf(xv.w), c3 = __cosf(xv.w);

    // per-wire Bloch components (only the ones the outputs need)
    float X0 = c0*C[4]  - s0*C[0];
    float Y0 = c0*C[5]  - s0*C[1];
    float z0 = c0*C[6]  - s0*C[2];
    float Y1 = s1*C[9]  + c1*C[13];
    float z1 = s1*C[10] + c1*C[14];
    float X3 = c3*C[20] - s3*C[16];
    float Y3 = c3*C[21] - s3*C[17];
    float z3 = c3*C[22] - s3*C[18];

    float A0=C[24], A1=C[25], A2=C[26], A3=C[27];
    float B0=C[28], B1=C[29], B2=C[30], B3=C[31];

    float z01 = z0*z1;
    float4 o;
    o.x = z3*(A0*z1 + B0*(X0*Y1));
    o.y = z0*(A1*z1 + B1*Y1);
    o.z = z01*(A2 + B2*X3);
    o.w = A3*(z01*z3) + B3*((Y0*Y1)*Y3);
    ((float4*)out)[b] = o;
}

extern "C" void kernel_launch(void* const* d_in, const int* in_sizes, int n_in,
                              void* d_out, int out_size, void* d_ws, size_t ws_size,
                              hipStream_t stream) {
    const float* inputs = (const float*)d_in[0];
    const float* theta  = (const float*)d_in[1];
    float* out = (float*)d_out;
    int n = in_sizes[0] / 4;
    int blocks = (n + 255) / 256;
    qsim_kernel<<<blocks, 256, 0, stream>>>(inputs, theta, out, n);
}